// Round 3
// baseline (238.789 us; speedup 1.0000x reference)
//
#include <hip/hip_runtime.h>

typedef __attribute__((ext_vector_type(4)))  float f32x4;
typedef __attribute__((ext_vector_type(16))) float f32x16;
typedef __attribute__((ext_vector_type(8)))  short bf16x8;

typedef __attribute__((address_space(1))) const void gvoid;
typedef __attribute__((address_space(3))) void lvoid;

__device__ __forceinline__ void gl_lds16(const void* g, void* l) {
  __builtin_amdgcn_global_load_lds((gvoid*)g, (lvoid*)l, 16, 0, 0);
}

__device__ __forceinline__ ushort f2bf(float f) {
  union { float f; unsigned u; } v; v.f = f;
  unsigned u = v.u;
  return (ushort)((u + 0x7fffu + ((u >> 16) & 1u)) >> 16);
}

__device__ __forceinline__ uint cvt_pk_bf16(float lo, float hi) {
  uint r;
  asm("v_cvt_pk_bf16_f32 %0, %1, %2" : "=v"(r) : "v"(lo), "v"(hi));
  return r;
}
__device__ __forceinline__ void plswap(uint& x, uint& y) {
  asm volatile("v_permlane32_swap_b32 %0, %1" : "+v"(x), "+v"(y));
}

// ---------------- X fp32 -> bf16 ----------------
__global__ __launch_bounds__(256) void cvt_x(const float* __restrict__ x,
                                             ushort* __restrict__ o) {
  int idx = blockIdx.x * 256 + threadIdx.x;
  float4 v = reinterpret_cast<const float4*>(x)[idx];
  ushort4 r;
  r.x = f2bf(v.x); r.y = f2bf(v.y); r.z = f2bf(v.z); r.w = f2bf(v.w);
  reinterpret_cast<ushort4*>(o)[idx] = r;
}

// ---------------- W fp32 [K][N] -> bf16 W^T [3][N][K] ----------------
__global__ __launch_bounds__(256) void wtrans(const float* __restrict__ Wq,
                                              const float* __restrict__ Wk,
                                              const float* __restrict__ Wv,
                                              ushort* __restrict__ WT) {
  __shared__ ushort tile[64 * 65];
  int bx = blockIdx.x;
  int w = bx >> 8;
  int rem = bx & 255;
  int k0 = (rem >> 4) << 6;
  int n0 = (rem & 15) << 6;
  const float* W = (w == 0) ? Wq : (w == 1) ? Wk : Wv;
  int tid = threadIdx.x;
#pragma unroll
  for (int it = 0; it < 16; ++it) {
    int idx = tid + it * 256;
    int r = idx >> 6, c = idx & 63;
    tile[r * 65 + c] = f2bf(W[(k0 + r) * 1024 + n0 + c]);
  }
  __syncthreads();
#pragma unroll
  for (int it = 0; it < 16; ++it) {
    int idx = tid + it * 256;
    int r = idx >> 6, c = idx & 63;
    WT[w * 1048576 + (n0 + r) * 1024 + k0 + c] = tile[c * 65 + r];
  }
}

// ---------------- fused QKV GEMM (m97-style) -------------------------------
// grid: (32, 24); block 256 (4 waves as 2x2, each 64x64 of a 128x128 tile)
__global__ __launch_bounds__(256) void qkv_gemm(
    const ushort* __restrict__ Xb, const ushort* __restrict__ WT,
    const float* __restrict__ bq, const float* __restrict__ bk,
    const float* __restrict__ bv, ushort* __restrict__ Qb,
    ushort* __restrict__ Kb, ushort* __restrict__ VT) {
  __shared__ ushort smem[128 * 136];      // 34816 B; staging uses first 32 KB
  ushort* Xs = smem;                      // [128][64] linear (for global_load_lds)
  ushort* Ws = smem + 8192;               // [128][64] linear
  int tid = threadIdx.x;
  int wave = tid >> 6, lane = tid & 63, g = lane >> 4, lr = lane & 15;
  int wr = wave >> 1, wc = wave & 1;
  int m0 = blockIdx.x << 7;
  int n0g = blockIdx.y << 7;
  f32x4 acc[4][4];
#pragma unroll
  for (int i = 0; i < 4; ++i)
#pragma unroll
    for (int j = 0; j < 4; ++j) { acc[i][j][0] = 0.f; acc[i][j][1] = 0.f; acc[i][j][2] = 0.f; acc[i][j][3] = 0.f; }

  int lrow = lane >> 3, lcol = (lane & 7) * 8;
  for (int k0 = 0; k0 < 1024; k0 += 64) {
    __syncthreads();                       // prev-iter LDS reads done
#pragma unroll
    for (int c = 0; c < 4; ++c) {
      int cw = wave * 4 + c;               // 1KB chunk id (wave-uniform)
      int row = cw * 8 + lrow;
      gl_lds16(Xb + (size_t)(m0 + row) * 1024 + k0 + lcol, Xs + cw * 512);
      gl_lds16(WT + (size_t)(n0g + row) * 1024 + k0 + lcol, Ws + cw * 512);
    }
    __syncthreads();                       // staged data visible
#pragma unroll
    for (int ks = 0; ks < 2; ++ks) {
      bf16x8 a[4], b[4];
#pragma unroll
      for (int mi = 0; mi < 4; ++mi)
        a[mi] = *reinterpret_cast<const bf16x8*>(&Xs[(wr * 64 + mi * 16 + lr) * 64 + ks * 32 + g * 8]);
#pragma unroll
      for (int ni = 0; ni < 4; ++ni)
        b[ni] = *reinterpret_cast<const bf16x8*>(&Ws[(wc * 64 + ni * 16 + lr) * 64 + ks * 32 + g * 8]);
      __builtin_amdgcn_s_setprio(1);
#pragma unroll
      for (int mi = 0; mi < 4; ++mi)
#pragma unroll
        for (int ni = 0; ni < 4; ++ni)
          acc[mi][ni] = __builtin_amdgcn_mfma_f32_16x16x32_bf16(a[mi], b[ni], acc[mi][ni], 0, 0, 0);
      __builtin_amdgcn_s_setprio(0);
    }
  }
  __syncthreads();

  int which = n0g >> 10;
  const float* bias = (which == 0) ? bq : (which == 1) ? bk : bv;
  int nloc0 = (n0g & 1023);
  if (which == 2) {
    // LDS layout [n(d) 0..127][m 0..127] stride 136 (transposed for V^T output)
#pragma unroll
    for (int ni = 0; ni < 4; ++ni) {
      int row = wc * 64 + ni * 16 + lr;
      float bb = bias[nloc0 + row];
#pragma unroll
      for (int mi = 0; mi < 4; ++mi) {
        int m = wr * 64 + mi * 16 + g * 4;
        ushort4 v4;
        v4.x = f2bf(acc[mi][ni][0] + bb);
        v4.y = f2bf(acc[mi][ni][1] + bb);
        v4.z = f2bf(acc[mi][ni][2] + bb);
        v4.w = f2bf(acc[mi][ni][3] + bb);
        *reinterpret_cast<ushort4*>(&smem[row * 136 + m]) = v4;
      }
    }
    __syncthreads();
    int b_ = m0 >> 11, s0 = m0 & 2047;
#pragma unroll
    for (int it = 0; it < 8; ++it) {
      int c = tid + it * 256;
      int row = c >> 4, mc = (c & 15) * 8;
      uint4 vv = *reinterpret_cast<const uint4*>(&smem[row * 136 + mc]);
      int n = nloc0 + row;
      int hh = n >> 6, dd = n & 63;
      *reinterpret_cast<uint4*>(&VT[((size_t)(b_ * 16 + hh) * 64 + dd) * 2048 + s0 + mc]) = vv;
    }
  } else {
    // LDS layout [m 0..127][n 0..127] stride 136
#pragma unroll
    for (int ni = 0; ni < 4; ++ni) {
      int n = wc * 64 + ni * 16 + lr;
      float bb = bias[nloc0 + n];
#pragma unroll
      for (int mi = 0; mi < 4; ++mi) {
#pragma unroll
        for (int r = 0; r < 4; ++r)
          smem[(wr * 64 + mi * 16 + g * 4 + r) * 136 + n] = f2bf(acc[mi][ni][r] + bb);
      }
    }
    __syncthreads();
    ushort* ob = (which == 0) ? Qb : Kb;
#pragma unroll
    for (int it = 0; it < 8; ++it) {
      int c = tid + it * 256;
      int row = c >> 4, nc = (c & 15) * 8;
      uint4 vv = *reinterpret_cast<const uint4*>(&smem[row * 136 + nc]);
      int m = m0 + row;
      int b_ = m >> 11, s = m & 2047;
      int n = nloc0 + nc;
      int hh = n >> 6, dd = n & 63;
      *reinterpret_cast<uint4*>(&ob[((size_t)(b_ * 16 + hh) * 2048 + s) * 64 + dd]) = vv;
    }
  }
}

// ---------------- flash attention: swapped QK^T, 32x32 MFMA ----------------
// grid: 512 = 16 pairs x 32 bh; block 256 (4 waves).
// waves 0,1 -> q-tile pi (strips +0,+32); waves 2,3 -> q-tile 31-pi.
__global__ __launch_bounds__(256) void attn(const ushort* __restrict__ Qb,
                                            const ushort* __restrict__ Kb,
                                            const ushort* __restrict__ VT,
                                            const float* __restrict__ mask,
                                            float* __restrict__ out) {
  __shared__ char smem[34816];
  ushort* Ks = (ushort*)smem;              // [64 kv][64 d], XOR-swizzled 16B units
  ushort* Vs = (ushort*)(smem + 8192);     // [64 d][64 kv], XOR-swizzled
  float*  Ms = (float*)(smem + 16384);     // [64] mask tile
  int tid = threadIdx.x;
  int wave = tid >> 6, lane = tid & 63;
  int hi = lane >> 5, l31 = lane & 31;
  int pi = blockIdx.x & 15, bh = blockIdx.x >> 4;
  int b_ = bh >> 4, h = bh & 15;
  const ushort* Qh = Qb + (size_t)bh * 2048 * 64;
  const ushort* Kh = Kb + (size_t)bh * 2048 * 64;
  const ushort* VTh = VT + (size_t)bh * 64 * 2048;

  int tile = (wave < 2) ? pi : (31 - pi);
  int q0w = tile * 64 + (wave & 1) * 32;   // this wave's 32 q rows
  int tmax = 31 - pi;

  bf16x8 aq[4];
#pragma unroll
  for (int ds = 0; ds < 4; ++ds)
    aq[ds] = *reinterpret_cast<const bf16x8*>(Qh + (q0w + l31) * 64 + ds * 16 + hi * 8);

  f32x16 Od0, Od1;
#pragma unroll
  for (int j = 0; j < 16; ++j) { Od0[j] = 0.f; Od1[j] = 0.f; }
  float mrun = -__builtin_inff(), lrun = 0.f;

  for (int t = 0; t <= tmax; ++t) {
    int kv0 = t << 6;
    __syncthreads();                       // prev tile reads done
#pragma unroll
    for (int c = 0; c < 2; ++c) {
      int ch = tid + (c << 8);
      int row = ch >> 3, e0 = (ch & 7) * 8, bc = (ch & 7) << 4;
      int sw = bc ^ ((row & 7) << 4);
      uint4 kvv = *reinterpret_cast<const uint4*>(Kh + (size_t)(kv0 + row) * 64 + e0);
      *reinterpret_cast<uint4*>((char*)Ks + row * 128 + sw) = kvv;
      uint4 vvv = *reinterpret_cast<const uint4*>(VTh + (size_t)row * 2048 + kv0 + e0);
      *reinterpret_cast<uint4*>((char*)Vs + row * 128 + sw) = vvv;
    }
    if (tid < 64) Ms[tid] = mask[b_ * 2048 + kv0 + tid];
    __syncthreads();

#pragma unroll
    for (int sub = 0; sub < 2; ++sub) {
      int kvb = kv0 + sub * 32;
      if (kvb > q0w) continue;             // fully masked (or inactive wave)
      bool dg = (kvb == q0w);

      // QK^T: S^T[kv][q] = K . Q^T
      f32x16 s;
#pragma unroll
      for (int j = 0; j < 16; ++j) s[j] = 0.f;
      __builtin_amdgcn_s_setprio(1);
#pragma unroll
      for (int ds = 0; ds < 4; ++ds) {
        int krow = sub * 32 + l31;
        bf16x8 kf = *reinterpret_cast<const bf16x8*>(
            (char*)Ks + krow * 128 + ((ds * 32 + hi * 16) ^ ((krow & 7) << 4)));
        s = __builtin_amdgcn_mfma_f32_32x32x16_bf16(kf, aq[ds], s, 0, 0, 0);
      }
      __builtin_amdgcn_s_setprio(0);

      // scale + additive mask (+ causal on diagonal sub-tile)
#pragma unroll
      for (int jj = 0; jj < 4; ++jj) {
        float4 mv4 = *reinterpret_cast<const float4*>(Ms + sub * 32 + jj * 8 + 4 * hi);
        const float* mvp = (const float*)&mv4;
#pragma unroll
        for (int r = 0; r < 4; ++r) {
          int j = jj * 4 + r;
          float sv = s[j] * 0.125f + mvp[r];
          if (dg) {
            int kvg = kvb + jj * 8 + 4 * hi + r;
            sv = (kvg > q0w + l31) ? -__builtin_inff() : sv;
          }
          s[j] = sv;
        }
      }

      // online softmax: lane-local column + one partner exchange
      float tmx = s[0];
#pragma unroll
      for (int j = 1; j < 16; ++j) tmx = fmaxf(tmx, s[j]);
      tmx = fmaxf(tmx, __shfl_xor(tmx, 32));
      bool defer = __all(tmx - mrun <= 8.0f);
      float al = 1.0f;
      if (!defer) {
        float nm = fmaxf(mrun, tmx);
        al = __expf(mrun - nm);
        mrun = nm;
      }
      float rs = 0.f;
#pragma unroll
      for (int j = 0; j < 16; ++j) {
        float p = __expf(s[j] - mrun);
        s[j] = p;
        rs += p;
      }
      rs += __shfl_xor(rs, 32);
      lrun = lrun * al + rs;
      if (!defer) {
#pragma unroll
        for (int j = 0; j < 16; ++j) { Od0[j] *= al; Od1[j] *= al; }
      }

      // P^T -> bf16 B-fragments via cvt_pk + permlane32_swap
      uint x0 = cvt_pk_bf16(s[0], s[1]),   y0 = cvt_pk_bf16(s[4], s[5]);
      uint x1 = cvt_pk_bf16(s[2], s[3]),   y1 = cvt_pk_bf16(s[6], s[7]);
      plswap(x0, y0); plswap(x1, y1);
      uint x2 = cvt_pk_bf16(s[8], s[9]),   y2 = cvt_pk_bf16(s[12], s[13]);
      uint x3 = cvt_pk_bf16(s[10], s[11]), y3 = cvt_pk_bf16(s[14], s[15]);
      plswap(x2, y2); plswap(x3, y3);
      union U { uint w[4]; bf16x8 v; };
      U pa0, pa1;
      pa0.w[0] = x0; pa0.w[1] = x1; pa0.w[2] = y0; pa0.w[3] = y1;
      pa1.w[0] = x2; pa1.w[1] = x3; pa1.w[2] = y2; pa1.w[3] = y3;

      // PV: O^T[d][q] += V^T . P^T
      __builtin_amdgcn_s_setprio(1);
#pragma unroll
      for (int ks = 0; ks < 2; ++ks) {
        bf16x8 pf = ks ? pa1.v : pa0.v;
        int bc = sub * 64 + ks * 32 + hi * 16;
        int r0 = l31, r1 = 32 + l31;
        bf16x8 v0 = *reinterpret_cast<const bf16x8*>((char*)Vs + r0 * 128 + (bc ^ ((r0 & 7) << 4)));
        Od0 = __builtin_amdgcn_mfma_f32_32x32x16_bf16(v0, pf, Od0, 0, 0, 0);
        bf16x8 v1 = *reinterpret_cast<const bf16x8*>((char*)Vs + r1 * 128 + (bc ^ ((r1 & 7) << 4)));
        Od1 = __builtin_amdgcn_mfma_f32_32x32x16_bf16(v1, pf, Od1, 0, 0, 0);
      }
      __builtin_amdgcn_s_setprio(0);
    }
  }

  __syncthreads();                          // all waves done with Ks/Vs
  // transpose O^T -> row-major via per-wave LDS, then coalesced store
  float rl = 1.0f / lrun;
  float* Ot = (float*)smem + wave * (32 * 68);
#pragma unroll
  for (int jj = 0; jj < 4; ++jj) {
    int d0a = jj * 8 + 4 * hi;
    float4 w0, w1;
    w0.x = Od0[jj * 4 + 0] * rl; w0.y = Od0[jj * 4 + 1] * rl;
    w0.z = Od0[jj * 4 + 2] * rl; w0.w = Od0[jj * 4 + 3] * rl;
    w1.x = Od1[jj * 4 + 0] * rl; w1.y = Od1[jj * 4 + 1] * rl;
    w1.z = Od1[jj * 4 + 2] * rl; w1.w = Od1[jj * 4 + 3] * rl;
    *reinterpret_cast<float4*>(&Ot[l31 * 68 + d0a]) = w0;
    *reinterpret_cast<float4*>(&Ot[l31 * 68 + 32 + d0a]) = w1;
  }
  // within-wave write->read; compiler inserts lgkmcnt waits
  int qr = lane >> 1, half = lane & 1;
  const float* Orow = &Ot[qr * 68 + half * 32];
  float* og = out + (size_t)(b_ * 2048 + q0w + qr) * 1024 + h * 64 + half * 32;
#pragma unroll
  for (int c2 = 0; c2 < 8; ++c2)
    *reinterpret_cast<float4*>(og + c2 * 4) = *reinterpret_cast<const float4*>(Orow + c2 * 4);
}

extern "C" void kernel_launch(void* const* d_in, const int* in_sizes, int n_in,
                              void* d_out, int out_size, void* d_ws, size_t ws_size,
                              hipStream_t stream) {
  const float* X    = (const float*)d_in[0];
  const float* mask = (const float*)d_in[1];
  const float* Wq   = (const float*)d_in[2];
  const float* bq   = (const float*)d_in[3];
  const float* Wk   = (const float*)d_in[4];
  const float* bk   = (const float*)d_in[5];
  const float* Wv   = (const float*)d_in[6];
  const float* bv   = (const float*)d_in[7];
  float* out = (float*)d_out;

  char* ws = (char*)d_ws;
  ushort* Xb  = (ushort*)ws;                         // 8 MB
  ushort* WTb = (ushort*)(ws + 8388608);             // 6 MB
  ushort* Qb  = (ushort*)(ws + 8388608 + 6291456);   // 8 MB
  ushort* Kb  = Qb + 4194304;                        // 8 MB
  ushort* VT  = Kb + 4194304;                        // 8 MB  [bh][d][S]

  cvt_x<<<4096, 256, 0, stream>>>(X, Xb);
  wtrans<<<768, 256, 0, stream>>>(Wq, Wk, Wv, WTb);
  qkv_gemm<<<dim3(32, 24), 256, 0, stream>>>(Xb, WTb, bq, bk, bv, Qb, Kb, VT);
  attn<<<512, 256, 0, stream>>>(Qb, Kb, VT, mask, out);
}

// Round 5
// 224.565 us; speedup vs baseline: 1.0633x; 1.0633x over previous
//
#include <hip/hip_runtime.h>

typedef __attribute__((ext_vector_type(4)))  float f32x4;
typedef __attribute__((ext_vector_type(16))) float f32x16;
typedef __attribute__((ext_vector_type(8)))  short bf16x8;

typedef __attribute__((address_space(1))) const void gvoid;
typedef __attribute__((address_space(3))) void lvoid;

__device__ __forceinline__ void gl_lds16(const void* g, void* l) {
  __builtin_amdgcn_global_load_lds((gvoid*)g, (lvoid*)l, 16, 0, 0);
}

__device__ __forceinline__ float exp2_fast(float x) {
  return __builtin_amdgcn_exp2f(x);
}

__device__ __forceinline__ ushort f2bf(float f) {
  union { float f; unsigned u; } v; v.f = f;
  unsigned u = v.u;
  return (ushort)((u + 0x7fffu + ((u >> 16) & 1u)) >> 16);
}

__device__ __forceinline__ uint cvt_pk_bf16(float lo, float hi) {
  uint r;
  asm("v_cvt_pk_bf16_f32 %0, %1, %2" : "=v"(r) : "v"(lo), "v"(hi));
  return r;
}
__device__ __forceinline__ void plswap(uint& x, uint& y) {
  asm volatile("v_permlane32_swap_b32 %0, %1" : "+v"(x), "+v"(y));
}

// ---------------- X fp32 -> bf16 ----------------
__global__ __launch_bounds__(256) void cvt_x(const float* __restrict__ x,
                                             ushort* __restrict__ o) {
  int idx = blockIdx.x * 256 + threadIdx.x;
  float4 v = reinterpret_cast<const float4*>(x)[idx];
  ushort4 r;
  r.x = f2bf(v.x); r.y = f2bf(v.y); r.z = f2bf(v.z); r.w = f2bf(v.w);
  reinterpret_cast<ushort4*>(o)[idx] = r;
}

// ---------------- W fp32 [K][N] -> bf16 W^T [3][N][K] ----------------
__global__ __launch_bounds__(256) void wtrans(const float* __restrict__ Wq,
                                              const float* __restrict__ Wk,
                                              const float* __restrict__ Wv,
                                              ushort* __restrict__ WT) {
  __shared__ ushort tile[64 * 68];
  int bx = blockIdx.x;
  int w = bx >> 8, rem = bx & 255;
  int k0 = (rem >> 4) << 6, n0 = (rem & 15) << 6;
  const float* W = (w == 0) ? Wq : (w == 1) ? Wk : Wv;
  int tid = threadIdx.x;
#pragma unroll
  for (int it = 0; it < 4; ++it) {
    int idx = tid + it * 256;
    int r = idx >> 4, c4 = (idx & 15) * 4;
    float4 v = *reinterpret_cast<const float4*>(&W[(k0 + r) * 1024 + n0 + c4]);
    ushort4 u;
    u.x = f2bf(v.x); u.y = f2bf(v.y); u.z = f2bf(v.z); u.w = f2bf(v.w);
    *reinterpret_cast<ushort4*>(&tile[r * 68 + c4]) = u;
  }
  __syncthreads();
#pragma unroll
  for (int it = 0; it < 4; ++it) {
    int idx = tid + it * 256;
    int n = idx >> 4, k4 = (idx & 15) * 4;
    ushort4 o;
    o.x = tile[(k4 + 0) * 68 + n];
    o.y = tile[(k4 + 1) * 68 + n];
    o.z = tile[(k4 + 2) * 68 + n];
    o.w = tile[(k4 + 3) * 68 + n];
    *reinterpret_cast<ushort4*>(&WT[w * 1048576 + (size_t)(n0 + n) * 1024 + k0 + k4]) = o;
  }
}

// ---------------- fused QKV GEMM (m97-style + T2 swizzle) -------------------
// grid: (32, 24); block 256 (4 waves as 2x2, each 64x64 of a 128x128 tile)
__global__ __launch_bounds__(256) void qkv_gemm(
    const ushort* __restrict__ Xb, const ushort* __restrict__ WT,
    const float* __restrict__ bq, const float* __restrict__ bk,
    const float* __restrict__ bv, ushort* __restrict__ Qb,
    ushort* __restrict__ Kb, ushort* __restrict__ VT) {
  __shared__ ushort smem[128 * 136];      // 34816 B; staging uses first 32 KB
  ushort* Xs = smem;                      // [128][64] linear, XOR-swizzled content
  ushort* Ws = smem + 8192;
  int tid = threadIdx.x;
  int wave = tid >> 6, lane = tid & 63, g = lane >> 4, lr = lane & 15;
  int wr = wave >> 1, wc = wave & 1;
  int m0 = blockIdx.x << 7;
  int n0g = blockIdx.y << 7;
  f32x4 acc[4][4];
#pragma unroll
  for (int i = 0; i < 4; ++i)
#pragma unroll
    for (int j = 0; j < 4; ++j) { acc[i][j][0] = 0.f; acc[i][j][1] = 0.f; acc[i][j][2] = 0.f; acc[i][j][3] = 0.f; }

  int l3 = lane >> 3;
  int jsw = ((lane & 7) ^ l3) * 8;        // pre-swizzled source column (elements)
  int swz = lr & 7;                       // frag-read row swizzle key
  for (int k0 = 0; k0 < 1024; k0 += 64) {
    __syncthreads();                       // prev-iter LDS reads done
#pragma unroll
    for (int c = 0; c < 4; ++c) {
      int cw = wave * 4 + c;               // 1KB chunk id (wave-uniform)
      int row = cw * 8 + l3;
      gl_lds16(Xb + (size_t)(m0 + row) * 1024 + k0 + jsw, Xs + cw * 512);
      gl_lds16(WT + (size_t)(n0g + row) * 1024 + k0 + jsw, Ws + cw * 512);
    }
    __syncthreads();                       // staged data visible
#pragma unroll
    for (int ks = 0; ks < 2; ++ks) {
      bf16x8 a[4], b[4];
      int slot = ((ks * 4 + g) ^ swz) * 8;
#pragma unroll
      for (int mi = 0; mi < 4; ++mi)
        a[mi] = *reinterpret_cast<const bf16x8*>(&Xs[(wr * 64 + mi * 16 + lr) * 64 + slot]);
#pragma unroll
      for (int ni = 0; ni < 4; ++ni)
        b[ni] = *reinterpret_cast<const bf16x8*>(&Ws[(wc * 64 + ni * 16 + lr) * 64 + slot]);
#pragma unroll
      for (int mi = 0; mi < 4; ++mi)
#pragma unroll
        for (int ni = 0; ni < 4; ++ni)
          acc[mi][ni] = __builtin_amdgcn_mfma_f32_16x16x32_bf16(a[mi], b[ni], acc[mi][ni], 0, 0, 0);
    }
  }
  __syncthreads();

  int which = n0g >> 10;
  const float* bias = (which == 0) ? bq : (which == 1) ? bk : bv;
  int nloc0 = (n0g & 1023);
  if (which == 2) {
    // LDS layout [n(d) 0..127][m 0..127] stride 136 (transposed for V^T output)
#pragma unroll
    for (int ni = 0; ni < 4; ++ni) {
      int row = wc * 64 + ni * 16 + lr;
      float bb = bias[nloc0 + row];
#pragma unroll
      for (int mi = 0; mi < 4; ++mi) {
        int m = wr * 64 + mi * 16 + g * 4;
        ushort4 v4;
        v4.x = f2bf(acc[mi][ni][0] + bb);
        v4.y = f2bf(acc[mi][ni][1] + bb);
        v4.z = f2bf(acc[mi][ni][2] + bb);
        v4.w = f2bf(acc[mi][ni][3] + bb);
        *reinterpret_cast<ushort4*>(&smem[row * 136 + m]) = v4;
      }
    }
    __syncthreads();
    int b_ = m0 >> 11, s0 = m0 & 2047;
#pragma unroll
    for (int it = 0; it < 8; ++it) {
      int c = tid + it * 256;
      int row = c >> 4, mc = (c & 15) * 8;
      uint4 vv = *reinterpret_cast<const uint4*>(&smem[row * 136 + mc]);
      int n = nloc0 + row;
      int hh = n >> 6, dd = n & 63;
      *reinterpret_cast<uint4*>(&VT[((size_t)(b_ * 16 + hh) * 64 + dd) * 2048 + s0 + mc]) = vv;
    }
  } else {
    // LDS layout [m 0..127][n 0..127] stride 136
#pragma unroll
    for (int ni = 0; ni < 4; ++ni) {
      int n = wc * 64 + ni * 16 + lr;
      float bb = bias[nloc0 + n];
#pragma unroll
      for (int mi = 0; mi < 4; ++mi) {
#pragma unroll
        for (int r = 0; r < 4; ++r)
          smem[(wr * 64 + mi * 16 + g * 4 + r) * 136 + n] = f2bf(acc[mi][ni][r] + bb);
      }
    }
    __syncthreads();
    ushort* ob = (which == 0) ? Qb : Kb;
#pragma unroll
    for (int it = 0; it < 8; ++it) {
      int c = tid + it * 256;
      int row = c >> 4, nc = (c & 15) * 8;
      uint4 vv = *reinterpret_cast<const uint4*>(&smem[row * 136 + nc]);
      int m = m0 + row;
      int b_ = m >> 11, s = m & 2047;
      int n = nloc0 + nc;
      int hh = n >> 6, dd = n & 63;
      *reinterpret_cast<uint4*>(&ob[((size_t)(b_ * 16 + hh) * 2048 + s) * 64 + dd]) = vv;
    }
  }
}

// ---------------- flash attention v4 ----------------
__device__ __forceinline__ void softmax_state(f32x16& s, float& mrun, float& lrun,
                                              f32x16& Od0, f32x16& Od1,
                                              bf16x8& p0, bf16x8& p1) {
  float tmx = s[0];
#pragma unroll
  for (int j = 1; j < 16; ++j) tmx = fmaxf(tmx, s[j]);
  tmx = fmaxf(tmx, __shfl_xor(tmx, 32));
  if (!__all(tmx - mrun <= 11.5f)) {      // defer-max (log2 domain, ~e^8)
    float nm = fmaxf(mrun, tmx);
    float al = exp2_fast(mrun - nm);
    mrun = nm;
    lrun *= al;
#pragma unroll
    for (int j = 0; j < 16; ++j) { Od0[j] *= al; Od1[j] *= al; }
  }
  float rs = 0.f;
#pragma unroll
  for (int j = 0; j < 16; ++j) { float p = exp2_fast(s[j] - mrun); s[j] = p; rs += p; }
  rs += __shfl_xor(rs, 32);
  lrun += rs;
  uint x0 = cvt_pk_bf16(s[0], s[1]),   y0 = cvt_pk_bf16(s[4], s[5]);
  uint x1 = cvt_pk_bf16(s[2], s[3]),   y1 = cvt_pk_bf16(s[6], s[7]);
  plswap(x0, y0); plswap(x1, y1);
  uint x2 = cvt_pk_bf16(s[8], s[9]),   y2 = cvt_pk_bf16(s[12], s[13]);
  uint x3 = cvt_pk_bf16(s[10], s[11]), y3 = cvt_pk_bf16(s[14], s[15]);
  plswap(x2, y2); plswap(x3, y3);
  union U { uint w[4]; bf16x8 v; } u0, u1;
  u0.w[0] = x0; u0.w[1] = x1; u0.w[2] = y0; u0.w[3] = y1;
  u1.w[0] = x2; u1.w[1] = x3; u1.w[2] = y2; u1.w[3] = y3;
  p0 = u0.v; p1 = u1.v;
}

__device__ __forceinline__ void attn_stage(const ushort* Kh, const ushort* VTh,
                                           const float* maskp, char* smem,
                                           int buf, int kv0, int tid, int jsw) {
  ushort* Ksb = (ushort*)(smem + buf * 16384);
  ushort* Vsb = Ksb + 4096;
  int wave = tid >> 6, lane = tid & 63;
  int l3 = lane >> 3;
#pragma unroll
  for (int c = 0; c < 4; ++c) {
    int ch = wave * 4 + c;
    int row = ch * 8 + l3;
    gl_lds16(Kh + (size_t)(kv0 + row) * 64 + jsw, Ksb + ch * 512);
    gl_lds16(VTh + (size_t)row * 2048 + kv0 + jsw, Vsb + ch * 512);
  }
  if (tid < 16) {
    float* Msb = (float*)(smem + 32768 + buf * 256);
    float4 m4 = *reinterpret_cast<const float4*>(maskp + kv0 + tid * 4);
    m4.x *= 1.44269504f; m4.y *= 1.44269504f; m4.z *= 1.44269504f; m4.w *= 1.44269504f;
    *reinterpret_cast<float4*>(Msb + tid * 4) = m4;
  }
}

__device__ __forceinline__ void attn_writeout(char* smem, int wave, int lane,
                                              const f32x16& Od0, const f32x16& Od1,
                                              float lrun, float* outp, int q0w) {
  float* Ot = (float*)smem + wave * 2176;
  int hi = lane >> 5, l31 = lane & 31;
  float rl = 1.0f / lrun;
#pragma unroll
  for (int jj = 0; jj < 4; ++jj) {
    int d0a = jj * 8 + 4 * hi;
    float4 w0, w1;
    w0.x = Od0[jj * 4 + 0] * rl; w0.y = Od0[jj * 4 + 1] * rl;
    w0.z = Od0[jj * 4 + 2] * rl; w0.w = Od0[jj * 4 + 3] * rl;
    w1.x = Od1[jj * 4 + 0] * rl; w1.y = Od1[jj * 4 + 1] * rl;
    w1.z = Od1[jj * 4 + 2] * rl; w1.w = Od1[jj * 4 + 3] * rl;
    *reinterpret_cast<float4*>(&Ot[l31 * 68 + d0a]) = w0;
    *reinterpret_cast<float4*>(&Ot[l31 * 68 + 32 + d0a]) = w1;
  }
  int qr = lane >> 1, half = lane & 1;
  const float* Orow = &Ot[qr * 68 + half * 32];
  float* og = outp + (size_t)(q0w + qr) * 1024 + half * 32;
#pragma unroll
  for (int c2 = 0; c2 < 8; ++c2)
    *reinterpret_cast<float4*>(og + c2 * 4) = *reinterpret_cast<const float4*>(Orow + c2 * 4);
}

// grid: 512 = 16 pairs x 32 bh; block 128 (2 waves).
// wave w carries strip w of tile pi AND strip w of tile 31-pi (dual state).
__global__ __launch_bounds__(128) void attn(const ushort* __restrict__ Qb,
                                            const ushort* __restrict__ Kb,
                                            const ushort* __restrict__ VT,
                                            const float* __restrict__ mask,
                                            float* __restrict__ out) {
  __shared__ char smem[33280];             // 2x(8K K + 8K V) + 2x256 mask
  const float SCALE = 0.125f * 1.44269504f;
  int tid = threadIdx.x;
  int wave = tid >> 6, lane = tid & 63;
  int hi = lane >> 5, l31 = lane & 31;
  int jsw = ((lane & 7) ^ (lane >> 3)) * 8;
  int pi = blockIdx.x & 15, bh = blockIdx.x >> 4;
  int b_ = bh >> 4, h = bh & 15;
  const ushort* Qh = Qb + (size_t)bh * 131072;
  const ushort* Kh = Kb + (size_t)bh * 131072;
  const ushort* VTh = VT + (size_t)bh * 131072;
  const float* maskp = mask + b_ * 2048;
  int qa0 = pi * 64 + wave * 32;
  int qb0 = (31 - pi) * 64 + wave * 32;
  int tmax = 31 - pi;

  bf16x8 aqa[4], aqb[4];
#pragma unroll
  for (int ds = 0; ds < 4; ++ds) {
    aqa[ds] = *reinterpret_cast<const bf16x8*>(Qh + (qa0 + l31) * 64 + ds * 16 + hi * 8);
    aqb[ds] = *reinterpret_cast<const bf16x8*>(Qh + (qb0 + l31) * 64 + ds * 16 + hi * 8);
  }

  f32x16 OA0, OA1, OB0, OB1;
#pragma unroll
  for (int j = 0; j < 16; ++j) { OA0[j] = 0.f; OA1[j] = 0.f; OB0[j] = 0.f; OB1[j] = 0.f; }
  float mA = -__builtin_inff(), lA = 0.f, mB = -__builtin_inff(), lB = 0.f;

  attn_stage(Kh, VTh, maskp, smem, 0, 0, tid, jsw);

  for (int t = 0; t <= tmax; ++t) {
    int cur = t & 1;
    __syncthreads();                       // buf[cur] loads drained; old readers done
    if (t < tmax) attn_stage(Kh, VTh, maskp, smem, cur ^ 1, (t + 1) << 6, tid, jsw);
    ushort* Ksb = (ushort*)(smem + cur * 16384);
    ushort* Vsb = Ksb + 4096;
    const float* Msb = (const float*)(smem + 32768 + cur * 256);
    int kv0 = t << 6;
#pragma unroll
    for (int sub = 0; sub < 2; ++sub) {
      int kvb = kv0 + sub * 32;
      bool actA = (kvb <= qa0), actB = (kvb <= qb0);
      if (!actB && !actA) continue;
      // shared K fragments
      bf16x8 kf[4];
      int krow = sub * 32 + l31;
      int ksw = krow & 7;
#pragma unroll
      for (int ds = 0; ds < 4; ++ds)
        kf[ds] = *reinterpret_cast<const bf16x8*>(Ksb + krow * 64 + (((ds * 2 + hi) ^ ksw) * 8));
      f32x16 sB, sA;
      __builtin_amdgcn_s_setprio(1);
      if (actB) {
#pragma unroll
        for (int j = 0; j < 16; ++j) sB[j] = 0.f;
#pragma unroll
        for (int ds = 0; ds < 4; ++ds)
          sB = __builtin_amdgcn_mfma_f32_32x32x16_bf16(kf[ds], aqb[ds], sB, 0, 0, 0);
      }
      if (actA) {
#pragma unroll
        for (int j = 0; j < 16; ++j) sA[j] = 0.f;
#pragma unroll
        for (int ds = 0; ds < 4; ++ds)
          sA = __builtin_amdgcn_mfma_f32_32x32x16_bf16(kf[ds], aqa[ds], sA, 0, 0, 0);
      }
      __builtin_amdgcn_s_setprio(0);

      float4 mv[4];
#pragma unroll
      for (int jj = 0; jj < 4; ++jj)
        mv[jj] = *reinterpret_cast<const float4*>(Msb + sub * 32 + jj * 8 + 4 * hi);

      bf16x8 pB0, pB1, pA0, pA1;
      if (actB) {
        bool dg = (kvb == qb0);
#pragma unroll
        for (int jj = 0; jj < 4; ++jj) {
          const float* mvp = (const float*)&mv[jj];
#pragma unroll
          for (int r = 0; r < 4; ++r) {
            int j = jj * 4 + r;
            float v = sB[j] * SCALE + mvp[r];
            if (dg) {
              int kvg = kvb + jj * 8 + 4 * hi + r;
              v = (kvg > qb0 + l31) ? -__builtin_inff() : v;
            }
            sB[j] = v;
          }
        }
        softmax_state(sB, mB, lB, OB0, OB1, pB0, pB1);
      }
      if (actA) {
        bool dg = (kvb == qa0);
#pragma unroll
        for (int jj = 0; jj < 4; ++jj) {
          const float* mvp = (const float*)&mv[jj];
#pragma unroll
          for (int r = 0; r < 4; ++r) {
            int j = jj * 4 + r;
            float v = sA[j] * SCALE + mvp[r];
            if (dg) {
              int kvg = kvb + jj * 8 + 4 * hi + r;
              v = (kvg > qa0 + l31) ? -__builtin_inff() : v;
            }
            sA[j] = v;
          }
        }
        softmax_state(sA, mA, lA, OA0, OA1, pA0, pA1);
      }

      // PV with shared V fragments
      __builtin_amdgcn_s_setprio(1);
#pragma unroll
      for (int ks = 0; ks < 2; ++ks) {
#pragma unroll
        for (int h2 = 0; h2 < 2; ++h2) {
          int drow = h2 * 32 + l31;
          bf16x8 vf = *reinterpret_cast<const bf16x8*>(
              Vsb + drow * 64 + (((sub * 4 + ks * 2 + hi) ^ (drow & 7)) * 8));
          if (actB) {
            f32x16& O = h2 ? OB1 : OB0;
            O = __builtin_amdgcn_mfma_f32_32x32x16_bf16(vf, ks ? pB1 : pB0, O, 0, 0, 0);
          }
          if (actA) {
            f32x16& O = h2 ? OA1 : OA0;
            O = __builtin_amdgcn_mfma_f32_32x32x16_bf16(vf, ks ? pA1 : pA0, O, 0, 0, 0);
          }
        }
      }
      __builtin_amdgcn_s_setprio(0);
    }
  }

  __syncthreads();
  float* outp = out + (size_t)b_ * 2048 * 1024 + h * 64;
  attn_writeout(smem, wave, lane, OA0, OA1, lA, outp, qa0);
  attn_writeout(smem, wave, lane, OB0, OB1, lB, outp, qb0);
}

extern "C" void kernel_launch(void* const* d_in, const int* in_sizes, int n_in,
                              void* d_out, int out_size, void* d_ws, size_t ws_size,
                              hipStream_t stream) {
  const float* X    = (const float*)d_in[0];
  const float* mask = (const float*)d_in[1];
  const float* Wq   = (const float*)d_in[2];
  const float* bq   = (const float*)d_in[3];
  const float* Wk   = (const float*)d_in[4];
  const float* bk   = (const float*)d_in[5];
  const float* Wv   = (const float*)d_in[6];
  const float* bv   = (const float*)d_in[7];
  float* out = (float*)d_out;

  char* ws = (char*)d_ws;
  ushort* Xb  = (ushort*)ws;                         // 8 MB
  ushort* WTb = (ushort*)(ws + 8388608);             // 6 MB
  ushort* Qb  = (ushort*)(ws + 8388608 + 6291456);   // 8 MB
  ushort* Kb  = Qb + 4194304;                        // 8 MB
  ushort* VT  = Kb + 4194304;                        // 8 MB  [bh][d][S]

  cvt_x<<<4096, 256, 0, stream>>>(X, Xb);
  wtrans<<<768, 256, 0, stream>>>(Wq, Wk, Wv, WTb);
  qkv_gemm<<<dim3(32, 24), 256, 0, stream>>>(Xb, WTb, bq, bk, bv, Qb, Kb, VT);
  attn<<<512, 128, 0, stream>>>(Qb, Kb, VT, mask, out);
}